// Round 1
// baseline (215.782 us; speedup 1.0000x reference)
//
#include <hip/hip_runtime.h>
#include <hip/hip_bf16.h>
#include <cstdint>
#include <cstddef>

// Problem constants: B=4, T=1024, E=512, H=64, d_k=8
#define T_DIM 1024
#define E_DIM 512
#define H_DIM 64

typedef short bf16x8 __attribute__((ext_vector_type(8)));
typedef float f32x4  __attribute__((ext_vector_type(4)));

// ---------------------------------------------------------------------------
// Kernel A: per-head attention with closed-form quantum projection.
// grid = B*H*4 = 1024 blocks, 256 threads. Block handles head (b,h), rows
// q*256..q*256+255. Full head proj (1024x8 fp32 = 32KB) lives in LDS; scores
// are bounded by d_k*scale = 2.83 so softmax needs no max subtraction.
// ---------------------------------------------------------------------------
__global__ __launch_bounds__(256, 4)
void qattn_kernel(const float* __restrict__ x,
                  const float* __restrict__ theta,
                  __hip_bfloat16* __restrict__ attn_out /* [4096][512] bf16 */)
{
    __shared__ float proj[T_DIM][8];   // 32 KB

    const int blk  = blockIdx.x;
    const int q    = blk & 3;
    const int head = blk >> 2;          // 0..255
    const int b    = head >> 6;
    const int h    = head & 63;
    const int tid  = threadIdx.x;

    float ct[8];
#pragma unroll
    for (int d = 0; d < 8; ++d) ct[d] = __cosf(theta[d]);

    const float* xbase = x + (size_t)b * T_DIM * E_DIM + h * 8;

    // Cooperatively build proj in LDS; thread keeps its own row (k==q) in regs.
    float p[8];
#pragma unroll
    for (int k = 0; k < 4; ++k) {
        const int r = tid + k * 256;
        const float4 v0 = *(const float4*)(xbase + (size_t)r * E_DIM);
        const float4 v1 = *(const float4*)(xbase + (size_t)r * E_DIM + 4);
        float pr[8] = {v0.x, v0.y, v0.z, v0.w, v1.x, v1.y, v1.z, v1.w};
#pragma unroll
        for (int d = 0; d < 8; ++d) {
            pr[d] = __cosf(pr[d]) * ct[d];
            proj[r][d] = pr[d];
        }
        if (k == q) {
#pragma unroll
            for (int d = 0; d < 8; ++d) p[d] = pr[d];
        }
    }
    __syncthreads();

    const int t = q * 256 + tid;
    float num[8] = {0.f, 0.f, 0.f, 0.f, 0.f, 0.f, 0.f, 0.f};
    float den = 0.f;

    // scale = 1/sqrt(8)
#pragma unroll 2
    for (int s = 0; s < T_DIM; ++s) {
        const float4 v0 = *(const float4*)(&proj[s][0]);  // broadcast read
        const float4 v1 = *(const float4*)(&proj[s][4]);
        float sc;
        sc = p[0] * v0.x;
        sc = fmaf(p[1], v0.y, sc);
        sc = fmaf(p[2], v0.z, sc);
        sc = fmaf(p[3], v0.w, sc);
        sc = fmaf(p[4], v1.x, sc);
        sc = fmaf(p[5], v1.y, sc);
        sc = fmaf(p[6], v1.z, sc);
        sc = fmaf(p[7], v1.w, sc);
        const float e = __expf(sc * 0.35355339059327373f);
        den += e;
        num[0] = fmaf(e, v0.x, num[0]);
        num[1] = fmaf(e, v0.y, num[1]);
        num[2] = fmaf(e, v0.z, num[2]);
        num[3] = fmaf(e, v0.w, num[3]);
        num[4] = fmaf(e, v1.x, num[4]);
        num[5] = fmaf(e, v1.y, num[5]);
        num[6] = fmaf(e, v1.z, num[6]);
        num[7] = fmaf(e, v1.w, num[7]);
    }

    const float inv = 1.0f / den;
    alignas(16) __hip_bfloat16 ob[8];
#pragma unroll
    for (int d = 0; d < 8; ++d) ob[d] = __float2bfloat16(num[d] * inv);
    *(uint4*)(attn_out + (size_t)(b * T_DIM + t) * E_DIM + h * 8) =
        *(const uint4*)ob;
}

// ---------------------------------------------------------------------------
// Kernel W: convert W_combine fp32 -> bf16 (262144 elems). grid 256 x 256 thr.
// ---------------------------------------------------------------------------
__global__ __launch_bounds__(256)
void wconv_kernel(const float* __restrict__ W, __hip_bfloat16* __restrict__ Wb)
{
    const int i = (blockIdx.x * 256 + threadIdx.x) * 4;
    const float4 v = *(const float4*)(W + i);
    alignas(8) __hip_bfloat16 ob[4] = {
        __float2bfloat16(v.x), __float2bfloat16(v.y),
        __float2bfloat16(v.z), __float2bfloat16(v.w)};
    *(uint2*)(Wb + i) = *(const uint2*)ob;
}

// ---------------------------------------------------------------------------
// Kernel B: out[4096][512] = attn_bf16 @ W_bf16^T + bias (fp32 out).
// W is stored [N][K] (row-major W_combine), i.e. B^T-layout GEMM (m97 style).
// 128x128 block tile, BK=32, 4 waves in 2x2, each wave 4x4 16x16x32 MFMAs.
// ---------------------------------------------------------------------------
#define BM 128
#define BN 128
#define BK 32

__global__ __launch_bounds__(256, 2)
void combine_gemm(const __hip_bfloat16* __restrict__ A,  // [4096][512]
                  const __hip_bfloat16* __restrict__ W,  // [512][512] (N,K)
                  const float* __restrict__ bias,        // [512]
                  float* __restrict__ out)               // [4096][512]
{
    __shared__ __hip_bfloat16 As[BM][BK];  // 8 KB
    __shared__ __hip_bfloat16 Bs[BN][BK];  // 8 KB

    const int tid  = threadIdx.x;
    const int lane = tid & 63;
    const int wave = tid >> 6;            // 0..3
    const int bm   = blockIdx.x;          // 0..31
    const int bn   = blockIdx.y;          // 0..3
    const int wm   = (wave & 1) * 64;
    const int wn   = (wave >> 1) * 64;
    const int rlo  = lane & 15;
    const int khi  = (lane >> 4) * 8;

    f32x4 acc[4][4] = {};

    for (int k0 = 0; k0 < E_DIM; k0 += BK) {
        if (k0) __syncthreads();   // previous-iter LDS readers done
#pragma unroll
        for (int pas = 0; pas < 2; ++pas) {
            // 512 16B chunks per tile; chunk c -> row c>>2, k-sub c&3.
            const int c   = pas * 256 + wave * 64 + lane;
            const int row = c >> 2;
            const int kc  = c & 3;
            const __hip_bfloat16* gA =
                A + (size_t)(bm * BM + row) * E_DIM + k0 + kc * 8;
            const __hip_bfloat16* gW =
                W + (size_t)(bn * BN + row) * E_DIM + k0 + kc * 8;
            // wave-uniform LDS base; HW scatters lane i at base + i*16
            char* lA = (char*)As + (size_t)(pas * 256 + wave * 64) * 16;
            char* lB = (char*)Bs + (size_t)(pas * 256 + wave * 64) * 16;
            __builtin_amdgcn_global_load_lds(
                (const __attribute__((address_space(1))) void*)gA,
                (__attribute__((address_space(3))) void*)lA, 16, 0, 0);
            __builtin_amdgcn_global_load_lds(
                (const __attribute__((address_space(1))) void*)gW,
                (__attribute__((address_space(3))) void*)lB, 16, 0, 0);
        }
        __syncthreads();           // drains vmcnt before barrier (m97 pattern)

        bf16x8 af[4], bf[4];
#pragma unroll
        for (int i = 0; i < 4; ++i)
            af[i] = *(const bf16x8*)&As[wm + i * 16 + rlo][khi];
#pragma unroll
        for (int j = 0; j < 4; ++j)
            bf[j] = *(const bf16x8*)&Bs[wn + j * 16 + rlo][khi];
#pragma unroll
        for (int i = 0; i < 4; ++i)
#pragma unroll
            for (int j = 0; j < 4; ++j)
                acc[i][j] = __builtin_amdgcn_mfma_f32_16x16x32_bf16(
                    af[i], bf[j], acc[i][j], 0, 0, 0);
    }

    // Epilogue: C/D layout col = lane&15, row = (lane>>4)*4 + reg
    const int row0 = bm * BM + wm;
    const int col0 = bn * BN + wn;
#pragma unroll
    for (int j = 0; j < 4; ++j) {
        const int col = col0 + j * 16 + rlo;
        const float bv = bias[col];
#pragma unroll
        for (int i = 0; i < 4; ++i) {
            const int rbase = row0 + i * 16 + (lane >> 4) * 4;
#pragma unroll
            for (int r = 0; r < 4; ++r)
                out[(size_t)(rbase + r) * E_DIM + col] = acc[i][j][r] + bv;
        }
    }
}

// ---------------------------------------------------------------------------
extern "C" void kernel_launch(void* const* d_in, const int* in_sizes, int n_in,
                              void* d_out, int out_size, void* d_ws,
                              size_t ws_size, hipStream_t stream)
{
    const float* x     = (const float*)d_in[0];  // [4,1024,512]
    const float* theta = (const float*)d_in[1];  // [8]
    const float* W     = (const float*)d_in[2];  // [512,512]
    const float* bias  = (const float*)d_in[3];  // [512]
    float* out = (float*)d_out;                  // [4,1024,512] fp32

    // ws layout: attn_bf16 [4096*512] = 4 MB, then W_bf16 [512*512] = 512 KB
    __hip_bfloat16* attn_bf = (__hip_bfloat16*)d_ws;
    __hip_bfloat16* w_bf    = (__hip_bfloat16*)((char*)d_ws + 4u * 1024u * 1024u);

    hipLaunchKernelGGL(qattn_kernel, dim3(1024), dim3(256), 0, stream,
                       x, theta, attn_bf);
    hipLaunchKernelGGL(wconv_kernel, dim3(256), dim3(256), 0, stream, W, w_bf);
    hipLaunchKernelGGL(combine_gemm, dim3(32, 4), dim3(256), 0, stream,
                       attn_bf, w_bf, bias, out);
}

// Round 3
// 214.192 us; speedup vs baseline: 1.0074x; 1.0074x over previous
//
#include <hip/hip_runtime.h>
#include <hip/hip_bf16.h>
#include <cstdint>
#include <cstddef>

// Problem constants: B=4, T=1024, E=512, H=64, d_k=8
#define T_DIM 1024
#define E_DIM 512

typedef short bf16x8 __attribute__((ext_vector_type(8)));
typedef float f32x4  __attribute__((ext_vector_type(4)));
typedef float f32x2  __attribute__((ext_vector_type(2)));

static __device__ __forceinline__ f32x2 fma2(f32x2 a, f32x2 b, f32x2 c) {
    return __builtin_elementwise_fma(a, b, c);
}

// ---------------------------------------------------------------------------
// Kernel A: per-head attention, R=4 rows/thread. grid = B*H = 256 blocks,
// 256 threads. Block handles one full head: proj (1024x8 fp32 = 32KB) in LDS,
// each thread owns rows k*256+tid (k=0..3). Scores bounded by d_k*scale=2.83
// so softmax needs no max subtraction. R=4 amortizes the broadcast
// ds_read_b128 pair over 4 rows (R=1 was LDS-pipe-bound: ~164us model = 156us
// measured). Packed f32x2 math encourages v_pk_fma_f32. Also folds W
// fp32->bf16 convert (4 elems/thread covers 512*512 exactly).
// ---------------------------------------------------------------------------
__global__ __launch_bounds__(256)
void qattn_kernel(const float* __restrict__ x,
                  const float* __restrict__ theta,
                  const float* __restrict__ W,
                  __hip_bfloat16* __restrict__ attn_out, // [4096][512] bf16
                  __hip_bfloat16* __restrict__ w_bf)     // [512][512] bf16
{
    __shared__ float proj[T_DIM][8];   // 32 KB

    const int head = blockIdx.x;        // 0..255
    const int b    = head >> 6;
    const int h    = head & 63;
    const int tid  = threadIdx.x;

    // Folded W convert: thread (head,tid) does 4 consecutive elements.
    {
        const int i = (head * 256 + tid) * 4;
        const float4 v = *(const float4*)(W + i);
        alignas(8) __hip_bfloat16 ob[4] = {
            __float2bfloat16(v.x), __float2bfloat16(v.y),
            __float2bfloat16(v.z), __float2bfloat16(v.w)};
        *(uint2*)(w_bf + i) = *(const uint2*)ob;
    }

    float ct[8];
#pragma unroll
    for (int d = 0; d < 8; ++d) ct[d] = __cosf(theta[d]);

    const float* xbase = x + (size_t)b * T_DIM * E_DIM + h * 8;

    // Build proj in LDS; thread keeps its own 4 rows in registers as f32x2[4].
    f32x2 p[4][4];
#pragma unroll
    for (int k = 0; k < 4; ++k) {
        const int r = k * 256 + tid;
        const float4 v0 = *(const float4*)(xbase + (size_t)r * E_DIM);
        const float4 v1 = *(const float4*)(xbase + (size_t)r * E_DIM + 4);
        float pr[8] = {v0.x, v0.y, v0.z, v0.w, v1.x, v1.y, v1.z, v1.w};
#pragma unroll
        for (int d = 0; d < 8; ++d) pr[d] = __cosf(pr[d]) * ct[d];
        *(f32x4*)(&proj[r][0]) = f32x4{pr[0], pr[1], pr[2], pr[3]};
        *(f32x4*)(&proj[r][4]) = f32x4{pr[4], pr[5], pr[6], pr[7]};
        p[k][0] = f32x2{pr[0], pr[1]};
        p[k][1] = f32x2{pr[2], pr[3]};
        p[k][2] = f32x2{pr[4], pr[5]};
        p[k][3] = f32x2{pr[6], pr[7]};
    }
    __syncthreads();

    f32x2 num[4][4] = {};
    float den[4] = {0.f, 0.f, 0.f, 0.f};

#pragma unroll 2
    for (int s = 0; s < T_DIM; ++s) {
        const f32x4 va = *(const f32x4*)(&proj[s][0]);  // broadcast read
        const f32x4 vb = *(const f32x4*)(&proj[s][4]);
        const f32x2 v0 = {va.x, va.y};
        const f32x2 v1 = {va.z, va.w};
        const f32x2 v2 = {vb.x, vb.y};
        const f32x2 v3 = {vb.z, vb.w};
#pragma unroll
        for (int k = 0; k < 4; ++k) {
            f32x2 c0 = p[k][0] * v0;
            c0 = fma2(p[k][1], v1, c0);
            f32x2 c1 = p[k][2] * v2;
            c1 = fma2(p[k][3], v3, c1);
            const f32x2 c = c0 + c1;
            const float sc = c.x + c.y;
            const float e = __expf(sc * 0.35355339059327373f);
            den[k] += e;
            const f32x2 e2 = {e, e};
            num[k][0] = fma2(e2, v0, num[k][0]);
            num[k][1] = fma2(e2, v1, num[k][1]);
            num[k][2] = fma2(e2, v2, num[k][2]);
            num[k][3] = fma2(e2, v3, num[k][3]);
        }
    }

#pragma unroll
    for (int k = 0; k < 4; ++k) {
        const int t = k * 256 + tid;
        const float inv = 1.0f / den[k];
        alignas(16) __hip_bfloat16 ob[8];
#pragma unroll
        for (int d = 0; d < 4; ++d) {
            ob[2 * d]     = __float2bfloat16(num[k][d].x * inv);
            ob[2 * d + 1] = __float2bfloat16(num[k][d].y * inv);
        }
        *(uint4*)(attn_out + (size_t)(b * T_DIM + t) * E_DIM + h * 8) =
            *(const uint4*)ob;
    }
}

// ---------------------------------------------------------------------------
// Kernel B: out[4096][512] = attn_bf16 @ W_bf16^T + bias (fp32 out).
// W stored [N][K] row-major (B^T GEMM, m97 style). 128x64 block tile, BK=32,
// grid = 32 x 8 = 256 blocks (1/CU). 4 waves 2x2; wave = 64x32 -> acc[4][2].
// FIX from round 2: B tile is 64 rows x 4 chunks = 256 chunks -> staged by
// ALL 256 threads in one pass (previous `tid<128` left Bs[32..63] as
// uninitialized LDS -> NaN through MFMA).
// ---------------------------------------------------------------------------
#define BM 128
#define BN 64
#define BK 32

__global__ __launch_bounds__(256, 2)
void combine_gemm(const __hip_bfloat16* __restrict__ A,  // [4096][512]
                  const __hip_bfloat16* __restrict__ Wb, // [512][512] (N,K)
                  const float* __restrict__ bias,        // [512]
                  float* __restrict__ out)               // [4096][512]
{
    __shared__ __hip_bfloat16 As[BM][BK];  // 8 KB
    __shared__ __hip_bfloat16 Bs[BN][BK];  // 4 KB

    const int tid  = threadIdx.x;
    const int lane = tid & 63;
    const int wave = tid >> 6;            // 0..3
    const int bm   = blockIdx.x;          // 0..31
    const int bn   = blockIdx.y;          // 0..7
    const int wm   = (wave & 1) * 64;
    const int wn   = (wave >> 1) * 32;
    const int rlo  = lane & 15;
    const int khi  = (lane >> 4) * 8;

    f32x4 acc[4][2] = {};

    for (int k0 = 0; k0 < E_DIM; k0 += BK) {
        if (k0) __syncthreads();
        // A tile: 128 rows x 4 chunks(16B) = 512 chunks, 2 passes of 256.
#pragma unroll
        for (int pas = 0; pas < 2; ++pas) {
            const int c   = pas * 256 + tid;
            const int row = c >> 2;
            const int kc  = c & 3;
            const __hip_bfloat16* gA =
                A + (size_t)(bm * BM + row) * E_DIM + k0 + kc * 8;
            char* lA = (char*)As + (size_t)(pas * 256 + wave * 64) * 16;
            __builtin_amdgcn_global_load_lds(
                (const __attribute__((address_space(1))) void*)gA,
                (__attribute__((address_space(3))) void*)lA, 16, 0, 0);
        }
        // B tile: 64 rows x 4 chunks = 256 chunks, one pass, all threads.
        {
            const int row = tid >> 2;
            const int kc  = tid & 3;
            const __hip_bfloat16* gW =
                Wb + (size_t)(bn * BN + row) * E_DIM + k0 + kc * 8;
            char* lB = (char*)Bs + (size_t)(wave * 64) * 16;
            __builtin_amdgcn_global_load_lds(
                (const __attribute__((address_space(1))) void*)gW,
                (__attribute__((address_space(3))) void*)lB, 16, 0, 0);
        }
        __syncthreads();

        bf16x8 af[4], bf[2];
#pragma unroll
        for (int i = 0; i < 4; ++i)
            af[i] = *(const bf16x8*)&As[wm + i * 16 + rlo][khi];
#pragma unroll
        for (int j = 0; j < 2; ++j)
            bf[j] = *(const bf16x8*)&Bs[wn + j * 16 + rlo][khi];
#pragma unroll
        for (int i = 0; i < 4; ++i)
#pragma unroll
            for (int j = 0; j < 2; ++j)
                acc[i][j] = __builtin_amdgcn_mfma_f32_16x16x32_bf16(
                    af[i], bf[j], acc[i][j], 0, 0, 0);
    }

    // Epilogue: C/D layout col = lane&15, row = (lane>>4)*4 + reg
    const int row0 = bm * BM + wm;
    const int col0 = bn * BN + wn;
#pragma unroll
    for (int j = 0; j < 2; ++j) {
        const int col = col0 + j * 16 + rlo;
        const float bv = bias[col];
#pragma unroll
        for (int i = 0; i < 4; ++i) {
            const int rbase = row0 + i * 16 + (lane >> 4) * 4;
#pragma unroll
            for (int r = 0; r < 4; ++r)
                out[(size_t)(rbase + r) * E_DIM + col] = acc[i][j][r] + bv;
        }
    }
}

// ---------------------------------------------------------------------------
extern "C" void kernel_launch(void* const* d_in, const int* in_sizes, int n_in,
                              void* d_out, int out_size, void* d_ws,
                              size_t ws_size, hipStream_t stream)
{
    const float* x     = (const float*)d_in[0];  // [4,1024,512]
    const float* theta = (const float*)d_in[1];  // [8]
    const float* W     = (const float*)d_in[2];  // [512,512]
    const float* bias  = (const float*)d_in[3];  // [512]
    float* out = (float*)d_out;                  // [4,1024,512] fp32

    // ws layout: attn_bf16 [4096*512] = 4 MB, then W_bf16 [512*512] = 512 KB
    __hip_bfloat16* attn_bf = (__hip_bfloat16*)d_ws;
    __hip_bfloat16* w_bf    = (__hip_bfloat16*)((char*)d_ws + 4u * 1024u * 1024u);

    hipLaunchKernelGGL(qattn_kernel, dim3(256), dim3(256), 0, stream,
                       x, theta, W, attn_bf, w_bf);
    hipLaunchKernelGGL(combine_gemm, dim3(32, 8), dim3(256), 0, stream,
                       attn_bf, w_bf, bias, out);
}

// Round 4
// 136.411 us; speedup vs baseline: 1.5819x; 1.5702x over previous
//
#include <hip/hip_runtime.h>
#include <hip/hip_bf16.h>
#include <cstdint>
#include <cstddef>

// Problem constants: B=4, T=1024, E=512, H=64, d_k=8
#define T_DIM 1024
#define E_DIM 512

typedef short bf16x8 __attribute__((ext_vector_type(8)));
typedef float f32x4  __attribute__((ext_vector_type(4)));

// ---------------------------------------------------------------------------
// Kernel A: MFMA attention. grid = 256 heads x 4 q-blocks = 1024 blocks,
// 256 threads (4 waves). Block stages full-head proj = cos(x)*cos(theta)
// into LDS (row layout projA for A/B score frags, transposed projT for the
// PV B frag), then each wave processes 64 queries x all 1024 keys.
//
// Scores: mfma 16x16x32 bf16, A=keys(m) B=queries(n), K=d padded 8->32
// (quad 0 lanes carry the real d=0..7 = one b128 proj row; quads 1-3 zero).
// C-layout: col=lane&15=query, row=quad*4+reg=key  [m89/m91 verified].
// exp on VALU (scores bounded by 8*0.3536=2.83 -> no max subtraction),
// pack bf16, write per-wave S tile in LDS, re-read as PV A-operand
// (A[m=lane&15][k=quad*8+j], m120 pattern). PV B-operand column n=8 is
// all-ones so output col 8 = sum(e) = den (free, consistent with num).
// No __syncthreads in the main loop (S is wave-private).
// ---------------------------------------------------------------------------
#define SSTRIDE 40   // S row stride in bf16 (80B: 16B-aligned, 2-way banks)

__global__ __launch_bounds__(256)
void qattn_mfma(const float* __restrict__ x,
                const float* __restrict__ theta,
                const float* __restrict__ W,
                __hip_bfloat16* __restrict__ attn_out, // [4096][512] bf16
                __hip_bfloat16* __restrict__ w_bf)     // [512][512] bf16
{
    __shared__ __hip_bfloat16 projA[T_DIM][8];     // [key][d]   16 KB
    __shared__ __hip_bfloat16 projT[8][1032];      // [d][key]   16.5 KB (pad)
    __shared__ __hip_bfloat16 S[4][64][SSTRIDE];   // per-wave   20 KB

    const int bid  = blockIdx.x;        // 0..1023
    const int head = bid >> 2;          // 0..255
    const int qb   = bid & 3;
    const int b    = head >> 6;
    const int h    = head & 63;
    const int tid  = threadIdx.x;
    const int lane = tid & 63;
    const int wv   = tid >> 6;
    const int rlo  = lane & 15;
    const int quad = lane >> 4;

    // Folded W fp32->bf16 convert (blocks 0..255 cover 512*512 exactly).
    if (bid < 256) {
        const int i = (bid * 256 + tid) * 4;
        const float4 v = *(const float4*)(W + i);
        alignas(8) __hip_bfloat16 ob[4] = {
            __float2bfloat16(v.x), __float2bfloat16(v.y),
            __float2bfloat16(v.z), __float2bfloat16(v.w)};
        *(uint2*)(w_bf + i) = *(const uint2*)ob;
    }

    float ct[8];
#pragma unroll
    for (int d = 0; d < 8; ++d) ct[d] = __cosf(theta[d]);

    // Stage full-head proj: 1024 rows, 4 rows/thread.
    const float* xb = x + (size_t)b * T_DIM * E_DIM + h * 8;
#pragma unroll
    for (int k = 0; k < 4; ++k) {
        const int r = k * 256 + tid;
        const float4 v0 = *(const float4*)(xb + (size_t)r * E_DIM);
        const float4 v1 = *(const float4*)(xb + (size_t)r * E_DIM + 4);
        float pr[8] = {v0.x, v0.y, v0.z, v0.w, v1.x, v1.y, v1.z, v1.w};
        alignas(16) __hip_bfloat16 rb[8];
#pragma unroll
        for (int d = 0; d < 8; ++d)
            rb[d] = __float2bfloat16(__cosf(pr[d]) * ct[d]);
        *(uint4*)&projA[r][0] = *(const uint4*)rb;
#pragma unroll
        for (int d = 0; d < 8; ++d) projT[d][r] = rb[d];
    }
    __syncthreads();

    const bf16x8 z8 = {};
    // all-ones bf16 frag for the den column (bf16 1.0 = 0x3f80)
    bf16x8 ones8;
#pragma unroll
    for (int j = 0; j < 8; ++j) ones8[j] = (short)0x3f80;

    // Query B-frags for this wave's 4 query tiles (quad 0 carries d=0..7).
    const int q0 = qb * 256 + wv * 64;
    bf16x8 bq[4];
#pragma unroll
    for (int tl = 0; tl < 4; ++tl)
        bq[tl] = (quad == 0) ? *(const bf16x8*)&projA[q0 + tl * 16 + rlo][0]
                             : z8;

    f32x4 nacc[4] = {};
    const float scale = 0.35355339059327373f;   // 1/sqrt(8)

    for (int kc = 0; kc < 32; ++kc) {           // 32-key chunks
        // ---- scores + exp -> S (two 16-key halves) ----
#pragma unroll
        for (int half = 0; half < 2; ++half) {
            const int key0 = kc * 32 + half * 16;
            const bf16x8 ka =
                (quad == 0) ? *(const bf16x8*)&projA[key0 + rlo][0] : z8;
#pragma unroll
            for (int tl = 0; tl < 4; ++tl) {
                f32x4 s = __builtin_amdgcn_mfma_f32_16x16x32_bf16(
                    ka, bq[tl], (f32x4){0.f, 0.f, 0.f, 0.f}, 0, 0, 0);
                alignas(8) __hip_bfloat16 eb[4];
#pragma unroll
                for (int r = 0; r < 4; ++r)
                    eb[r] = __float2bfloat16(__expf(s[r] * scale));
                // lane holds query t=tl*16+rlo, keys key0+quad*4+r
                *(uint2*)&S[wv][tl * 16 + rlo][half * 16 + quad * 4] =
                    *(const uint2*)eb;
            }
        }
        // ---- PV over these 32 keys ----
        const bf16x8 bv = (rlo < 8)
            ? *(const bf16x8*)&projT[rlo][kc * 32 + quad * 8]
            : ((rlo == 8) ? ones8 : z8);
#pragma unroll
        for (int tl = 0; tl < 4; ++tl) {
            const bf16x8 sa =
                *(const bf16x8*)&S[wv][tl * 16 + rlo][quad * 8];
            nacc[tl] = __builtin_amdgcn_mfma_f32_16x16x32_bf16(
                sa, bv, nacc[tl], 0, 0, 0);
        }
    }

    // Epilogue: nacc[tl][r] = num[q=tl*16+quad*4+r][d=rlo]; col 8 = den.
    const int denSrc = (lane & 48) | 8;   // lane with rlo==8 in same quad
#pragma unroll
    for (int tl = 0; tl < 4; ++tl) {
#pragma unroll
        for (int r = 0; r < 4; ++r) {
            const float den = __shfl(nacc[tl][r], denSrc);
            if (rlo < 8) {
                const int trow = q0 + tl * 16 + quad * 4 + r;
                attn_out[(size_t)(b * T_DIM + trow) * E_DIM + h * 8 + rlo] =
                    __float2bfloat16(nacc[tl][r] / den);
            }
        }
    }
}

// ---------------------------------------------------------------------------
// Kernel B: out[4096][512] = attn_bf16 @ W_bf16^T + bias (fp32 out).
// Unchanged from round 3 (verified correct). 128x64 tile, BK=32, grid 32x8.
// ---------------------------------------------------------------------------
#define BM 128
#define BN 64
#define BK 32

__global__ __launch_bounds__(256, 2)
void combine_gemm(const __hip_bfloat16* __restrict__ A,  // [4096][512]
                  const __hip_bfloat16* __restrict__ Wb, // [512][512] (N,K)
                  const float* __restrict__ bias,        // [512]
                  float* __restrict__ out)               // [4096][512]
{
    __shared__ __hip_bfloat16 As[BM][BK];  // 8 KB
    __shared__ __hip_bfloat16 Bs[BN][BK];  // 4 KB

    const int tid  = threadIdx.x;
    const int lane = tid & 63;
    const int wave = tid >> 6;
    const int bm   = blockIdx.x;
    const int bn   = blockIdx.y;
    const int wm   = (wave & 1) * 64;
    const int wn   = (wave >> 1) * 32;
    const int rlo  = lane & 15;
    const int khi  = (lane >> 4) * 8;

    f32x4 acc[4][2] = {};

    for (int k0 = 0; k0 < E_DIM; k0 += BK) {
        if (k0) __syncthreads();
#pragma unroll
        for (int pas = 0; pas < 2; ++pas) {
            const int c   = pas * 256 + tid;
            const int row = c >> 2;
            const int kc  = c & 3;
            const __hip_bfloat16* gA =
                A + (size_t)(bm * BM + row) * E_DIM + k0 + kc * 8;
            char* lA = (char*)As + (size_t)(pas * 256 + wave * 64) * 16;
            __builtin_amdgcn_global_load_lds(
                (const __attribute__((address_space(1))) void*)gA,
                (__attribute__((address_space(3))) void*)lA, 16, 0, 0);
        }
        {
            const int row = tid >> 2;
            const int kc  = tid & 3;
            const __hip_bfloat16* gW =
                Wb + (size_t)(bn * BN + row) * E_DIM + k0 + kc * 8;
            char* lB = (char*)Bs + (size_t)(wave * 64) * 16;
            __builtin_amdgcn_global_load_lds(
                (const __attribute__((address_space(1))) void*)gW,
                (__attribute__((address_space(3))) void*)lB, 16, 0, 0);
        }
        __syncthreads();

        bf16x8 af[4], bf[2];
#pragma unroll
        for (int i = 0; i < 4; ++i)
            af[i] = *(const bf16x8*)&As[wm + i * 16 + rlo][khi];
#pragma unroll
        for (int j = 0; j < 2; ++j)
            bf[j] = *(const bf16x8*)&Bs[wn + j * 16 + rlo][khi];
#pragma unroll
        for (int i = 0; i < 4; ++i)
#pragma unroll
            for (int j = 0; j < 2; ++j)
                acc[i][j] = __builtin_amdgcn_mfma_f32_16x16x32_bf16(
                    af[i], bf[j], acc[i][j], 0, 0, 0);
    }

    const int row0 = bm * BM + wm;
    const int col0 = bn * BN + wn;
#pragma unroll
    for (int j = 0; j < 2; ++j) {
        const int col = col0 + j * 16 + rlo;
        const float bv = bias[col];
#pragma unroll
        for (int i = 0; i < 4; ++i) {
            const int rbase = row0 + i * 16 + (lane >> 4) * 4;
#pragma unroll
            for (int r = 0; r < 4; ++r)
                out[(size_t)(rbase + r) * E_DIM + col] = acc[i][j][r] + bv;
        }
    }
}

// ---------------------------------------------------------------------------
extern "C" void kernel_launch(void* const* d_in, const int* in_sizes, int n_in,
                              void* d_out, int out_size, void* d_ws,
                              size_t ws_size, hipStream_t stream)
{
    const float* x     = (const float*)d_in[0];  // [4,1024,512]
    const float* theta = (const float*)d_in[1];  // [8]
    const float* W     = (const float*)d_in[2];  // [512,512]
    const float* bias  = (const float*)d_in[3];  // [512]
    float* out = (float*)d_out;                  // [4,1024,512] fp32

    __hip_bfloat16* attn_bf = (__hip_bfloat16*)d_ws;
    __hip_bfloat16* w_bf    = (__hip_bfloat16*)((char*)d_ws + 4u * 1024u * 1024u);

    hipLaunchKernelGGL(qattn_mfma, dim3(1024), dim3(256), 0, stream,
                       x, theta, W, attn_bf, w_bf);
    hipLaunchKernelGGL(combine_gemm, dim3(32, 8), dim3(256), 0, stream,
                       attn_bf, w_bf, bias, out);
}

// Round 5
// 119.263 us; speedup vs baseline: 1.8093x; 1.1438x over previous
//
#include <hip/hip_runtime.h>
#include <hip/hip_bf16.h>
#include <cstdint>
#include <cstddef>

// Problem constants: B=4, T=1024, E=512, H=64, d_k=8
#define T_DIM 1024
#define E_DIM 512

typedef short bf16x8 __attribute__((ext_vector_type(8)));
typedef float f32x4  __attribute__((ext_vector_type(4)));

// ---------------------------------------------------------------------------
// Kernel A: MFMA attention, S-round-trip-free. grid = 256 heads x 4 q-blocks
// = 1024 blocks, 256 threads. proj staged in LDS twice: projA (row layout,
// PRE-SCALED by sqrt(scale*log2e)=0.7142255 so score MFMA output is directly
// the exp2 argument) and projT (transposed, unscaled, for the PV V-frag).
//
// Scores: mfma 16x16x32 bf16, A=keys B=queries (quad0 carries d=0..7).
// C-layout col=lane&15=query, row=quad*4+r=key [m89/m91]. After exp2, lane
// (quad,rlo) holds e for query rlo, keys {kc*32+quad*4+r} U {+16}. KEY IDEA:
// PV sums over k, so any k-permutation applied to BOTH operands is legal.
// We use pi(quad,j) = exactly the key order the score MFMAs produced, so the
// e-values feed the PV A-operand (A[m=rlo][k=quad*8+j]) with ZERO cross-lane
// movement (no S LDS buffer, no bank conflicts, -20KB LDS -> 4 blocks/CU).
// The V B-frag reads projT columns in the same pi order (two b64 reads).
// B col n=8 = ones -> output col 8 = sum(e) = den (pi-invariant).
// ---------------------------------------------------------------------------
__global__ __launch_bounds__(256)
void qattn_mfma(const float* __restrict__ x,
                const float* __restrict__ theta,
                const float* __restrict__ W,
                __hip_bfloat16* __restrict__ attn_out, // [4096][512] bf16
                __hip_bfloat16* __restrict__ w_bf)     // [512][512] bf16
{
    __shared__ __hip_bfloat16 projA[T_DIM][8];     // [key][d] scaled, 16 KB
    __shared__ __hip_bfloat16 projT[8][1032];      // [d][key] unscaled, 16.1 KB

    const int bid  = blockIdx.x;        // 0..1023
    const int head = bid >> 2;          // 0..255
    const int qb   = bid & 3;
    const int b    = head >> 6;
    const int h    = head & 63;
    const int tid  = threadIdx.x;
    const int lane = tid & 63;
    const int wv   = tid >> 6;
    const int rlo  = lane & 15;
    const int quad = lane >> 4;

    // Folded W fp32->bf16 convert (blocks 0..255 cover 512*512 exactly).
    if (bid < 256) {
        const int i = (bid * 256 + tid) * 4;
        const float4 v = *(const float4*)(W + i);
        alignas(8) __hip_bfloat16 ob[4] = {
            __float2bfloat16(v.x), __float2bfloat16(v.y),
            __float2bfloat16(v.z), __float2bfloat16(v.w)};
        *(uint2*)(w_bf + i) = *(const uint2*)ob;
    }

    // sqrt( (1/sqrt(8)) * log2(e) ) : folds softmax scale AND ln->log2 into
    // the score operands so e = exp2(raw mfma output), zero VALU muls.
    const float SA = 0.7142255f;
    float ctT[8], ctA[8];
#pragma unroll
    for (int d = 0; d < 8; ++d) {
        ctT[d] = __cosf(theta[d]);
        ctA[d] = ctT[d] * SA;
    }

    // Stage full-head proj: 1024 rows, 4 rows/thread.
    const float* xb = x + (size_t)b * T_DIM * E_DIM + h * 8;
#pragma unroll
    for (int k = 0; k < 4; ++k) {
        const int r = k * 256 + tid;
        const float4 v0 = *(const float4*)(xb + (size_t)r * E_DIM);
        const float4 v1 = *(const float4*)(xb + (size_t)r * E_DIM + 4);
        float pr[8] = {v0.x, v0.y, v0.z, v0.w, v1.x, v1.y, v1.z, v1.w};
        alignas(16) __hip_bfloat16 ra[8];
#pragma unroll
        for (int d = 0; d < 8; ++d) {
            const float c = __cosf(pr[d]);
            ra[d] = __float2bfloat16(c * ctA[d]);
            projT[d][r] = __float2bfloat16(c * ctT[d]);
        }
        *(uint4*)&projA[r][0] = *(const uint4*)ra;
    }
    __syncthreads();

    const bf16x8 z8 = {};
    bf16x8 ones8;
#pragma unroll
    for (int j = 0; j < 8; ++j) ones8[j] = (short)0x3f80;  // bf16 1.0

    // Query B-frags for this wave's 4 query tiles (quad 0 carries d=0..7).
    const int q0 = qb * 256 + wv * 64;
    bf16x8 bq[4];
#pragma unroll
    for (int tl = 0; tl < 4; ++tl)
        bq[tl] = (quad == 0) ? *(const bf16x8*)&projA[q0 + tl * 16 + rlo][0]
                             : z8;

    f32x4 nacc[4] = {};

    for (int kc = 0; kc < 32; ++kc) {           // 32-key chunks
        const int key0 = kc * 32;
        // V-frag in pi order: cols {key0+quad*4+j} U {key0+16+quad*4+j}.
        bf16x8 bv;
        if (rlo < 8) {
            const __hip_bfloat16* pt = &projT[rlo][key0 + quad * 4];
            union { uint2 u[2]; bf16x8 v; } uu;
            uu.u[0] = *(const uint2*)pt;
            uu.u[1] = *(const uint2*)(pt + 16);
            bv = uu.v;
        } else {
            bv = (rlo == 8) ? ones8 : z8;
        }
        // Key A-frags for the two 16-key halves.
        const bf16x8 ka0 =
            (quad == 0) ? *(const bf16x8*)&projA[key0 + rlo][0] : z8;
        const bf16x8 ka1 =
            (quad == 0) ? *(const bf16x8*)&projA[key0 + 16 + rlo][0] : z8;

#pragma unroll
        for (int tl = 0; tl < 4; ++tl) {
            f32x4 s0 = __builtin_amdgcn_mfma_f32_16x16x32_bf16(
                ka0, bq[tl], (f32x4){0.f, 0.f, 0.f, 0.f}, 0, 0, 0);
            f32x4 s1 = __builtin_amdgcn_mfma_f32_16x16x32_bf16(
                ka1, bq[tl], (f32x4){0.f, 0.f, 0.f, 0.f}, 0, 0, 0);
            alignas(16) __hip_bfloat16 af8[8];
#pragma unroll
            for (int r = 0; r < 4; ++r) {
                af8[r]     = __float2bfloat16(__builtin_amdgcn_exp2f(s0[r]));
                af8[4 + r] = __float2bfloat16(__builtin_amdgcn_exp2f(s1[r]));
            }
            nacc[tl] = __builtin_amdgcn_mfma_f32_16x16x32_bf16(
                *(const bf16x8*)af8, bv, nacc[tl], 0, 0, 0);
        }
    }

    // Epilogue: nacc[tl][r] = num[q=q0+tl*16+quad*4+r][d=rlo]; col 8 = den.
    const int denSrc = (lane & 48) | 8;   // lane with rlo==8 in same quad
#pragma unroll
    for (int tl = 0; tl < 4; ++tl) {
#pragma unroll
        for (int r = 0; r < 4; ++r) {
            const float den = __shfl(nacc[tl][r], denSrc);
            if (rlo < 8) {
                const int trow = q0 + tl * 16 + quad * 4 + r;
                attn_out[(size_t)(b * T_DIM + trow) * E_DIM + h * 8 + rlo] =
                    __float2bfloat16(nacc[tl][r] / den);
            }
        }
    }
}

// ---------------------------------------------------------------------------
// Kernel B: out[4096][512] = attn_bf16 @ W_bf16^T + bias (fp32 out).
// Retiled 64x64 (was 128x64): grid 64x8 = 512 blocks -> 2 blocks/CU for
// latency hiding (256 blocks = 1/CU had zero co-residency). BK=32.
// 4 waves 2x2, each 32x32 -> acc[2][2] of 16x16x32 MFMAs.
// ---------------------------------------------------------------------------
#define BM 64
#define BN 64
#define BK 32

__global__ __launch_bounds__(256, 2)
void combine_gemm(const __hip_bfloat16* __restrict__ A,  // [4096][512]
                  const __hip_bfloat16* __restrict__ Wb, // [512][512] (N,K)
                  const float* __restrict__ bias,        // [512]
                  float* __restrict__ out)               // [4096][512]
{
    __shared__ __hip_bfloat16 As[BM][BK];  // 4 KB
    __shared__ __hip_bfloat16 Bs[BN][BK];  // 4 KB

    const int tid  = threadIdx.x;
    const int lane = tid & 63;
    const int wave = tid >> 6;
    const int bm   = blockIdx.x;          // 0..63
    const int bn   = blockIdx.y;          // 0..7
    const int wm   = (wave & 1) * 32;
    const int wn   = (wave >> 1) * 32;
    const int rlo  = lane & 15;
    const int khi  = (lane >> 4) * 8;

    f32x4 acc[2][2] = {};

    for (int k0 = 0; k0 < E_DIM; k0 += BK) {
        if (k0) __syncthreads();
        // Each tile: 64 rows x 4 chunks(16B) = 256 chunks = 256 threads.
        {
            const int row = tid >> 2;
            const int kc  = tid & 3;
            const __hip_bfloat16* gA =
                A + (size_t)(bm * BM + row) * E_DIM + k0 + kc * 8;
            char* lA = (char*)As + (size_t)(wave * 64) * 16;
            __builtin_amdgcn_global_load_lds(
                (const __attribute__((address_space(1))) void*)gA,
                (__attribute__((address_space(3))) void*)lA, 16, 0, 0);
            const __hip_bfloat16* gW =
                Wb + (size_t)(bn * BN + row) * E_DIM + k0 + kc * 8;
            char* lB = (char*)Bs + (size_t)(wave * 64) * 16;
            __builtin_amdgcn_global_load_lds(
                (const __attribute__((address_space(1))) void*)gW,
                (__attribute__((address_space(3))) void*)lB, 16, 0, 0);
        }
        __syncthreads();

        bf16x8 af[2], bf[2];
#pragma unroll
        for (int i = 0; i < 2; ++i)
            af[i] = *(const bf16x8*)&As[wm + i * 16 + rlo][khi];
#pragma unroll
        for (int j = 0; j < 2; ++j)
            bf[j] = *(const bf16x8*)&Bs[wn + j * 16 + rlo][khi];
#pragma unroll
        for (int i = 0; i < 2; ++i)
#pragma unroll
            for (int j = 0; j < 2; ++j)
                acc[i][j] = __builtin_amdgcn_mfma_f32_16x16x32_bf16(
                    af[i], bf[j], acc[i][j], 0, 0, 0);
    }

    const int row0 = bm * BM + wm;
    const int col0 = bn * BN + wn;
#pragma unroll
    for (int j = 0; j < 2; ++j) {
        const int col = col0 + j * 16 + rlo;
        const float bv = bias[col];
#pragma unroll
        for (int i = 0; i < 2; ++i) {
            const int rbase = row0 + i * 16 + (lane >> 4) * 4;
#pragma unroll
            for (int r = 0; r < 4; ++r)
                out[(size_t)(rbase + r) * E_DIM + col] = acc[i][j][r] + bv;
        }
    }
}

// ---------------------------------------------------------------------------
extern "C" void kernel_launch(void* const* d_in, const int* in_sizes, int n_in,
                              void* d_out, int out_size, void* d_ws,
                              size_t ws_size, hipStream_t stream)
{
    const float* x     = (const float*)d_in[0];  // [4,1024,512]
    const float* theta = (const float*)d_in[1];  // [8]
    const float* W     = (const float*)d_in[2];  // [512,512]
    const float* bias  = (const float*)d_in[3];  // [512]
    float* out = (float*)d_out;                  // [4,1024,512] fp32

    __hip_bfloat16* attn_bf = (__hip_bfloat16*)d_ws;
    __hip_bfloat16* w_bf    = (__hip_bfloat16*)((char*)d_ws + 4u * 1024u * 1024u);

    hipLaunchKernelGGL(qattn_mfma, dim3(1024), dim3(256), 0, stream,
                       x, theta, W, attn_bf, w_bf);
    hipLaunchKernelGGL(combine_gemm, dim3(64, 8), dim3(256), 0, stream,
                       attn_bf, w_bf, bias, out);
}

// Round 6
// 109.794 us; speedup vs baseline: 1.9653x; 1.0862x over previous
//
#include <hip/hip_runtime.h>
#include <hip/hip_bf16.h>
#include <cstdint>
#include <cstddef>

// Problem constants: B=4, T=1024, E=512, H=64, d_k=8
#define T_DIM 1024
#define E_DIM 512

typedef short bf16x8 __attribute__((ext_vector_type(8)));
typedef float f32x4  __attribute__((ext_vector_type(4)));

// ---------------------------------------------------------------------------
// Kernel A: MFMA attention, one block per head (1024 thr, 16 waves).
// R5->R6: merged the 4 q-blocks of a head into one block -> x is read ONCE
// per head (FETCH 35MB -> ~10MB) and the cos/cvt staging runs once instead
// of 4x. Inner loop identical to R5 (verified): scores via 16x16x32 bf16
// MFMA (quad0 carries d=0..7; projA pre-scaled by sqrt(scale*log2e) so
// e = exp2(raw score)); the e-values feed the PV A-operand directly in the
// k-permutation the score MFMA produced (pi trick, zero cross-lane traffic,
// zero bank conflicts); V B-frag reads projT in the same pi order; B col 8
// = ones gives den for free in output col 8.
// ---------------------------------------------------------------------------
__global__ __launch_bounds__(1024)
void qattn_mfma(const float* __restrict__ x,
                const float* __restrict__ theta,
                const float* __restrict__ W,
                __hip_bfloat16* __restrict__ attn_out, // [4096][512] bf16
                __hip_bfloat16* __restrict__ w_bf)     // [512][512] bf16
{
    __shared__ __hip_bfloat16 projA[T_DIM][8];     // [key][d] scaled, 16 KB
    __shared__ __hip_bfloat16 projT[8][1032];      // [d][key] unscaled, 16.1 KB

    const int head = blockIdx.x;        // 0..255
    const int b    = head >> 6;
    const int h    = head & 63;
    const int tid  = threadIdx.x;       // 0..1023
    const int lane = tid & 63;
    const int wv   = tid >> 6;          // 0..15
    const int rlo  = lane & 15;
    const int quad = lane >> 4;

    // Folded W fp32->bf16 convert: global threads 0..65535 cover 512*512/4.
    {
        const int gid = head * 1024 + tid;
        if (gid < 65536) {
            const float4 v = *(const float4*)(W + gid * 4);
            alignas(8) __hip_bfloat16 ob[4] = {
                __float2bfloat16(v.x), __float2bfloat16(v.y),
                __float2bfloat16(v.z), __float2bfloat16(v.w)};
            *(uint2*)(w_bf + gid * 4) = *(const uint2*)ob;
        }
    }

    // sqrt( (1/sqrt(8)) * log2(e) ): folds softmax scale + ln->log2 into the
    // score operands so e = exp2(raw mfma output).
    const float SA = 0.7142255f;
    float ctT[8], ctA[8];
#pragma unroll
    for (int d = 0; d < 8; ++d) {
        ctT[d] = __cosf(theta[d]);
        ctA[d] = ctT[d] * SA;
    }

    // Stage full-head proj: 1024 rows, ONE row per thread.
    const float* xb = x + (size_t)b * T_DIM * E_DIM + h * 8;
    {
        const int r = tid;
        const float4 v0 = *(const float4*)(xb + (size_t)r * E_DIM);
        const float4 v1 = *(const float4*)(xb + (size_t)r * E_DIM + 4);
        float pr[8] = {v0.x, v0.y, v0.z, v0.w, v1.x, v1.y, v1.z, v1.w};
        alignas(16) __hip_bfloat16 ra[8];
#pragma unroll
        for (int d = 0; d < 8; ++d) {
            const float c = __cosf(pr[d]);
            ra[d] = __float2bfloat16(c * ctA[d]);
            projT[d][r] = __float2bfloat16(c * ctT[d]);
        }
        *(uint4*)&projA[r][0] = *(const uint4*)ra;
    }
    __syncthreads();

    const bf16x8 z8 = {};
    bf16x8 ones8;
#pragma unroll
    for (int j = 0; j < 8; ++j) ones8[j] = (short)0x3f80;  // bf16 1.0

    // Query B-frags for this wave's 64 queries (quad 0 carries d=0..7).
    const int q0 = wv * 64;
    bf16x8 bq[4];
#pragma unroll
    for (int tl = 0; tl < 4; ++tl)
        bq[tl] = (quad == 0) ? *(const bf16x8*)&projA[q0 + tl * 16 + rlo][0]
                             : z8;

    f32x4 nacc[4] = {};

    for (int kc = 0; kc < 32; ++kc) {           // 32-key chunks
        const int key0 = kc * 32;
        // V-frag in pi order: cols {key0+quad*4+j} U {key0+16+quad*4+j}.
        bf16x8 bv;
        if (rlo < 8) {
            const __hip_bfloat16* pt = &projT[rlo][key0 + quad * 4];
            union { uint2 u[2]; bf16x8 v; } uu;
            uu.u[0] = *(const uint2*)pt;
            uu.u[1] = *(const uint2*)(pt + 16);
            bv = uu.v;
        } else {
            bv = (rlo == 8) ? ones8 : z8;
        }
        // Key A-frags for the two 16-key halves.
        const bf16x8 ka0 =
            (quad == 0) ? *(const bf16x8*)&projA[key0 + rlo][0] : z8;
        const bf16x8 ka1 =
            (quad == 0) ? *(const bf16x8*)&projA[key0 + 16 + rlo][0] : z8;

#pragma unroll
        for (int tl = 0; tl < 4; ++tl) {
            f32x4 s0 = __builtin_amdgcn_mfma_f32_16x16x32_bf16(
                ka0, bq[tl], (f32x4){0.f, 0.f, 0.f, 0.f}, 0, 0, 0);
            f32x4 s1 = __builtin_amdgcn_mfma_f32_16x16x32_bf16(
                ka1, bq[tl], (f32x4){0.f, 0.f, 0.f, 0.f}, 0, 0, 0);
            alignas(16) __hip_bfloat16 af8[8];
#pragma unroll
            for (int r = 0; r < 4; ++r) {
                af8[r]     = __float2bfloat16(__builtin_amdgcn_exp2f(s0[r]));
                af8[4 + r] = __float2bfloat16(__builtin_amdgcn_exp2f(s1[r]));
            }
            nacc[tl] = __builtin_amdgcn_mfma_f32_16x16x32_bf16(
                *(const bf16x8*)af8, bv, nacc[tl], 0, 0, 0);
        }
    }

    // Epilogue: nacc[tl][r] = num[q=q0+tl*16+quad*4+r][d=rlo]; col 8 = den.
    const int denSrc = (lane & 48) | 8;   // lane with rlo==8 in same quad
#pragma unroll
    for (int tl = 0; tl < 4; ++tl) {
#pragma unroll
        for (int r = 0; r < 4; ++r) {
            const float den = __shfl(nacc[tl][r], denSrc);
            if (rlo < 8) {
                const int trow = q0 + tl * 16 + quad * 4 + r;
                attn_out[(size_t)(b * T_DIM + trow) * E_DIM + h * 8 + rlo] =
                    __float2bfloat16(nacc[tl][r] / den);
            }
        }
    }
}

// ---------------------------------------------------------------------------
// Kernel B: out[4096][512] = attn_bf16 @ W_bf16^T + bias (fp32 out).
// R6: back to 128x64 tile (R5's 64x64 regressed: 4 MFMAs/barrier was
// barrier-dominated) and widened to BK=64 -> 8 K-iters of 16 MFMAs.
// LDS k-chunks XOR-swizzled by row (chunk kc stored at slot kc^(row&7)) so
// the b128 fragment reads spread over all 32 banks (the unswizzled layout
// put all 16 rows of a fragment on the same 4 banks = 16-way conflict).
// global_load_lds lane-scatter is honored: LDS slot order == lane order,
// each lane just fetches the XOR-matched global chunk (same 128B lines).
// ---------------------------------------------------------------------------
#define BM 128
#define BN 64
#define BK 64

__global__ __launch_bounds__(256, 2)
void combine_gemm(const __hip_bfloat16* __restrict__ A,  // [4096][512]
                  const __hip_bfloat16* __restrict__ Wb, // [512][512] (N,K)
                  const float* __restrict__ bias,        // [512]
                  float* __restrict__ out)               // [4096][512]
{
    __shared__ __hip_bfloat16 As[BM][BK];  // 16 KB
    __shared__ __hip_bfloat16 Bs[BN][BK];  // 8 KB

    const int tid  = threadIdx.x;
    const int lane = tid & 63;
    const int wave = tid >> 6;
    const int bm   = blockIdx.x;          // 0..31
    const int bn   = blockIdx.y;          // 0..7
    const int wm   = (wave & 1) * 64;
    const int wn   = (wave >> 1) * 32;
    const int rlo  = lane & 15;
    const int quad = lane >> 4;

    f32x4 acc[4][2] = {};

    for (int k0 = 0; k0 < E_DIM; k0 += BK) {
        if (k0) __syncthreads();
        // A: 128 rows x 8 chunks(16B) = 1024 chunks, 4 passes of 256.
#pragma unroll
        for (int p = 0; p < 4; ++p) {
            const int c   = p * 256 + tid;
            const int row = c >> 3;
            const int kcs = c & 7;                 // LDS slot
            const int kc  = kcs ^ (row & 7);       // global chunk (swizzle)
            const __hip_bfloat16* gA =
                A + (size_t)(bm * BM + row) * E_DIM + k0 + kc * 8;
            char* lA = (char*)As + (size_t)(p * 256 + wave * 64) * 16;
            __builtin_amdgcn_global_load_lds(
                (const __attribute__((address_space(1))) void*)gA,
                (__attribute__((address_space(3))) void*)lA, 16, 0, 0);
        }
        // B: 64 rows x 8 chunks = 512 chunks, 2 passes of 256.
#pragma unroll
        for (int p = 0; p < 2; ++p) {
            const int c   = p * 256 + tid;
            const int row = c >> 3;
            const int kcs = c & 7;
            const int kc  = kcs ^ (row & 7);
            const __hip_bfloat16* gW =
                Wb + (size_t)(bn * BN + row) * E_DIM + k0 + kc * 8;
            char* lB = (char*)Bs + (size_t)(p * 256 + wave * 64) * 16;
            __builtin_amdgcn_global_load_lds(
                (const __attribute__((address_space(1))) void*)gW,
                (__attribute__((address_space(3))) void*)lB, 16, 0, 0);
        }
        __syncthreads();

#pragma unroll
        for (int ks = 0; ks < 2; ++ks) {
            const int kci  = ks * 4 + quad;              // wanted k-chunk
            const int koff = (kci ^ (rlo & 7)) * 8;      // swizzled LDS off
            bf16x8 af[4], bf[2];
#pragma unroll
            for (int i = 0; i < 4; ++i)
                af[i] = *(const bf16x8*)&As[wm + i * 16 + rlo][koff];
#pragma unroll
            for (int j = 0; j < 2; ++j)
                bf[j] = *(const bf16x8*)&Bs[wn + j * 16 + rlo][koff];
#pragma unroll
            for (int i = 0; i < 4; ++i)
#pragma unroll
                for (int j = 0; j < 2; ++j)
                    acc[i][j] = __builtin_amdgcn_mfma_f32_16x16x32_bf16(
                        af[i], bf[j], acc[i][j], 0, 0, 0);
        }
    }

    // Epilogue: C/D layout col = lane&15, row = (lane>>4)*4 + reg.
    const int row0 = bm * BM + wm;
    const int col0 = bn * BN + wn;
#pragma unroll
    for (int j = 0; j < 2; ++j) {
        const int col = col0 + j * 16 + rlo;
        const float bv = bias[col];
#pragma unroll
        for (int i = 0; i < 4; ++i) {
            const int rbase = row0 + i * 16 + quad * 4;
#pragma unroll
            for (int r = 0; r < 4; ++r)
                out[(size_t)(rbase + r) * E_DIM + col] = acc[i][j][r] + bv;
        }
    }
}

// ---------------------------------------------------------------------------
extern "C" void kernel_launch(void* const* d_in, const int* in_sizes, int n_in,
                              void* d_out, int out_size, void* d_ws,
                              size_t ws_size, hipStream_t stream)
{
    const float* x     = (const float*)d_in[0];  // [4,1024,512]
    const float* theta = (const float*)d_in[1];  // [8]
    const float* W     = (const float*)d_in[2];  // [512,512]
    const float* bias  = (const float*)d_in[3];  // [512]
    float* out = (float*)d_out;                  // [4,1024,512] fp32

    __hip_bfloat16* attn_bf = (__hip_bfloat16*)d_ws;
    __hip_bfloat16* w_bf    = (__hip_bfloat16*)((char*)d_ws + 4u * 1024u * 1024u);

    hipLaunchKernelGGL(qattn_mfma, dim3(256), dim3(1024), 0, stream,
                       x, theta, W, attn_bf, w_bf);
    hipLaunchKernelGGL(combine_gemm, dim3(32, 8), dim3(256), 0, stream,
                       attn_bf, w_bf, bias, out);
}